// Round 1
// baseline (286.027 us; speedup 1.0000x reference)
//
#include <hip/hip_runtime.h>

#define D_F 128
#define N_NODES 10000
#define N_EDGES 320000
#define TE 64
#define EDGE_THREADS 512
#define EDGE_BLOCKS 256

typedef short s16x8 __attribute__((ext_vector_type(8)));
typedef float f32x4 __attribute__((ext_vector_type(4)));

__device__ __forceinline__ unsigned short f2bf(float f) {
  union { float f; unsigned u; } v; v.f = f;
  unsigned r = v.u + 0x7FFFu + ((v.u >> 16) & 1u);
  return (unsigned short)(r >> 16);
}
__device__ __forceinline__ float silu_f(float x) { return x / (1.0f + __expf(-x)); }

// ---- LDS map (bytes) ----
// we1t: [128 col][256 k] bf16, row stride 512B, swizzle byte^=((col&7)<<4) on k-part
// we2t: [128 col][128 k] bf16, row stride 256B, same swizzle
// a_t : [64 e][256 k] bf16, row 512B, swizzle on e
// m1t : [64 e][128 k] bf16, row 256B, swizzle on e
#define OFF_WE1T 0u
#define OFF_WE2T 65536u
#define OFF_A    98304u
#define OFF_M1   131072u
#define OFF_META 147456u
#define EDGE_LDS (147456u + 2304u)

__global__ __launch_bounds__(EDGE_THREADS)
void egcl_edge_kernel(const float* __restrict__ h, const float* __restrict__ coord,
                      const float* __restrict__ edge_mask,
                      const float* __restrict__ We1, const float* __restrict__ be1,
                      const float* __restrict__ We2, const float* __restrict__ be2,
                      const int* __restrict__ ei, float* __restrict__ agg) {
  extern __shared__ __attribute__((aligned(16))) char smem[];
  const int tid = threadIdx.x;

  int*   rows = (int*)(smem + OFF_META);
  float* rads = (float*)(smem + OFF_META + 256);
  float* msks = (float*)(smem + OFF_META + 512);
  float* be1s = (float*)(smem + OFF_META + 768);
  float* be2s = (float*)(smem + OFF_META + 1280);
  float* wls  = (float*)(smem + OFF_META + 1792);

  // ---- stage weights once (transposed, bf16, swizzled) ----
  for (int i = tid; i < 256 * 128; i += EDGE_THREADS) {
    int k = i >> 7, col = i & 127;
    *(unsigned short*)(smem + OFF_WE1T + (unsigned)(col * 512) +
                       (unsigned)((k * 2) ^ ((col & 7) << 4))) = f2bf(We1[i]);
  }
  for (int i = tid; i < 128 * 128; i += EDGE_THREADS) {
    int k = i >> 7, col = i & 127;
    *(unsigned short*)(smem + OFF_WE2T + (unsigned)(col * 256) +
                       (unsigned)((k * 2) ^ ((col & 7) << 4))) = f2bf(We2[i]);
  }
  if (tid < 128) { be1s[tid] = be1[tid]; be2s[tid] = be2[tid]; wls[tid] = We1[256 * 128 + tid]; }
  __syncthreads();

  const int lane = tid & 63;
  const int wv   = tid >> 6;   // 0..7
  const int eg   = wv >> 2;    // 0..1 : edge half
  const int cg   = wv & 3;     // 0..3 : col quarter
  const int l15  = lane & 15;
  const int lg   = lane >> 4;  // 0..3
  const int e0   = eg * 32;
  const int c0   = cg * 32;
  const int ar0  = e0 + l15, ar1 = ar0 + 16;
  const int bc0  = c0 + l15, bc1 = bc0 + 16;
  const unsigned swz = (unsigned)((l15 & 7) << 4);  // same for row and row+16 (16 % 8 == 0)

  const int ntiles = N_EDGES / TE;
  for (int tile = (int)blockIdx.x; tile < ntiles; tile += (int)gridDim.x) {
    const int ebase = tile * TE;

    // ---- meta: row, radial, mask ----
    if (tid < TE) {
      int r = ei[ebase + tid];
      int c = ei[N_EDGES + ebase + tid];
      float dx = coord[r * 3 + 0] - coord[c * 3 + 0];
      float dy = coord[r * 3 + 1] - coord[c * 3 + 1];
      float dz = coord[r * 3 + 2] - coord[c * 3 + 2];
      rows[tid] = r;
      rads[tid] = dx * dx + dy * dy + dz * dz;
      msks[tid] = edge_mask[ebase + tid];
    }
    // ---- stage A tile: a_t[e][0:128]=h[row], [128:256]=h[col], bf16 ----
    {
      const int e = tid >> 3, sub = tid & 7;
      const unsigned eswz = (unsigned)((e & 7) << 4);
      const unsigned arow = OFF_A + (unsigned)(e * 512);
#pragma unroll
      for (int p = 0; p < 2; ++p) {
        int node = ei[p * N_EDGES + ebase + e];
        const f32x4* src = (const f32x4*)(h + node * D_F + sub * 16);
        f32x4 x0 = src[0], x1 = src[1], x2 = src[2], x3 = src[3];
        s16x8 v0, v1;
        v0[0] = (short)f2bf(x0[0]); v0[1] = (short)f2bf(x0[1]);
        v0[2] = (short)f2bf(x0[2]); v0[3] = (short)f2bf(x0[3]);
        v0[4] = (short)f2bf(x1[0]); v0[5] = (short)f2bf(x1[1]);
        v0[6] = (short)f2bf(x1[2]); v0[7] = (short)f2bf(x1[3]);
        v1[0] = (short)f2bf(x2[0]); v1[1] = (short)f2bf(x2[1]);
        v1[2] = (short)f2bf(x2[2]); v1[3] = (short)f2bf(x2[3]);
        v1[4] = (short)f2bf(x3[0]); v1[5] = (short)f2bf(x3[1]);
        v1[6] = (short)f2bf(x3[2]); v1[7] = (short)f2bf(x3[3]);
        unsigned kb = (unsigned)(p * 256 + sub * 32);
        *(s16x8*)(smem + arow + (kb ^ eswz)) = v0;
        *(s16x8*)(smem + arow + ((kb + 16u) ^ eswz)) = v1;
      }
    }
    __syncthreads();

    // ---- GEMM1: [64x256] @ We1t -> m1 ----
    f32x4 acc[2][2];
#pragma unroll
    for (int i = 0; i < 2; ++i)
#pragma unroll
      for (int j = 0; j < 2; ++j) acc[i][j] = (f32x4){0.f, 0.f, 0.f, 0.f};
    {
      const char* a0p = smem + OFF_A + (unsigned)(ar0 * 512);
      const char* a1p = smem + OFF_A + (unsigned)(ar1 * 512);
      const char* b0p = smem + OFF_WE1T + (unsigned)(bc0 * 512);
      const char* b1p = smem + OFF_WE1T + (unsigned)(bc1 * 512);
#pragma unroll
      for (int ks = 0; ks < 8; ++ks) {
        unsigned kb = (unsigned)((ks * 32 + lg * 8) * 2) ^ swz;
        s16x8 a0 = *(const s16x8*)(a0p + kb);
        s16x8 a1 = *(const s16x8*)(a1p + kb);
        s16x8 b0 = *(const s16x8*)(b0p + kb);
        s16x8 b1 = *(const s16x8*)(b1p + kb);
        acc[0][0] = __builtin_amdgcn_mfma_f32_16x16x32_bf16(a0, b0, acc[0][0], 0, 0, 0);
        acc[0][1] = __builtin_amdgcn_mfma_f32_16x16x32_bf16(a0, b1, acc[0][1], 0, 0, 0);
        acc[1][0] = __builtin_amdgcn_mfma_f32_16x16x32_bf16(a1, b0, acc[1][0], 0, 0, 0);
        acc[1][1] = __builtin_amdgcn_mfma_f32_16x16x32_bf16(a1, b1, acc[1][1], 0, 0, 0);
      }
      // epilogue: + be1 + radial*wlast, silu, -> m1t bf16
#pragma unroll
      for (int ti = 0; ti < 2; ++ti) {
#pragma unroll
        for (int tj = 0; tj < 2; ++tj) {
          int colc = c0 + tj * 16 + l15;
          float bv = be1s[colc], wl = wls[colc];
#pragma unroll
          for (int q = 0; q < 4; ++q) {
            int e = e0 + ti * 16 + lg * 4 + q;
            float v = acc[ti][tj][q] + bv + rads[e] * wl;
            v = silu_f(v);
            *(unsigned short*)(smem + OFF_M1 + (unsigned)(e * 256) +
                               (unsigned)((colc * 2) ^ ((e & 7) << 4))) = f2bf(v);
          }
        }
      }
    }
    __syncthreads();

    // ---- GEMM2: m1 @ We2t -> silu -> *mask -> atomicAdd agg ----
#pragma unroll
    for (int i = 0; i < 2; ++i)
#pragma unroll
      for (int j = 0; j < 2; ++j) acc[i][j] = (f32x4){0.f, 0.f, 0.f, 0.f};
    {
      const char* a0p = smem + OFF_M1 + (unsigned)(ar0 * 256);
      const char* a1p = smem + OFF_M1 + (unsigned)(ar1 * 256);
      const char* b0p = smem + OFF_WE2T + (unsigned)(bc0 * 256);
      const char* b1p = smem + OFF_WE2T + (unsigned)(bc1 * 256);
#pragma unroll
      for (int ks = 0; ks < 4; ++ks) {
        unsigned kb = (unsigned)((ks * 32 + lg * 8) * 2) ^ swz;
        s16x8 a0 = *(const s16x8*)(a0p + kb);
        s16x8 a1 = *(const s16x8*)(a1p + kb);
        s16x8 b0 = *(const s16x8*)(b0p + kb);
        s16x8 b1 = *(const s16x8*)(b1p + kb);
        acc[0][0] = __builtin_amdgcn_mfma_f32_16x16x32_bf16(a0, b0, acc[0][0], 0, 0, 0);
        acc[0][1] = __builtin_amdgcn_mfma_f32_16x16x32_bf16(a0, b1, acc[0][1], 0, 0, 0);
        acc[1][0] = __builtin_amdgcn_mfma_f32_16x16x32_bf16(a1, b0, acc[1][0], 0, 0, 0);
        acc[1][1] = __builtin_amdgcn_mfma_f32_16x16x32_bf16(a1, b1, acc[1][1], 0, 0, 0);
      }
#pragma unroll
      for (int ti = 0; ti < 2; ++ti) {
#pragma unroll
        for (int tj = 0; tj < 2; ++tj) {
          int colc = c0 + tj * 16 + l15;
          float bv = be2s[colc];
#pragma unroll
          for (int q = 0; q < 4; ++q) {
            int e = e0 + ti * 16 + lg * 4 + q;
            float v = silu_f(acc[ti][tj][q] + bv) * msks[e];
            atomicAdd(agg + rows[e] * D_F + colc, v);
          }
        }
      }
    }
    __syncthreads();
  }
}

// ---- node MLP: fp32, one wave per node ----
__global__ __launch_bounds__(256)
void egcl_node_kernel(const float* __restrict__ h, const float* __restrict__ agg,
                      const float* __restrict__ Wn1, const float* __restrict__ bn1,
                      const float* __restrict__ Wn2, const float* __restrict__ bn2,
                      float* __restrict__ out) {
  const int wv = threadIdx.x >> 6, lane = threadIdx.x & 63;
  const int n = blockIdx.x * 4 + wv;
  __shared__ float nin[4][256];
  __shared__ float hid[4][128];
  {
    const f32x4* hp = (const f32x4*)(h + n * D_F);
    const f32x4* ap = (const f32x4*)(agg + n * D_F);
    if (lane < 32) ((f32x4*)nin[wv])[lane] = hp[lane];
    else           ((f32x4*)nin[wv])[lane] = ap[lane - 32];
  }
  __syncthreads();
  const int c = lane * 2;
  float a0 = bn1[c], a1 = bn1[c + 1];
#pragma unroll 8
  for (int k = 0; k < 256; ++k) {
    float x = nin[wv][k];
    float2 w = *(const float2*)(Wn1 + k * D_F + c);
    a0 += x * w.x; a1 += x * w.y;
  }
  hid[wv][c]     = silu_f(a0);
  hid[wv][c + 1] = silu_f(a1);
  __syncthreads();
  float o0 = bn2[c], o1 = bn2[c + 1];
#pragma unroll 8
  for (int k = 0; k < 128; ++k) {
    float x = hid[wv][k];
    float2 w = *(const float2*)(Wn2 + k * D_F + c);
    o0 += x * w.x; o1 += x * w.y;
  }
  out[n * D_F + c]     = h[n * D_F + c] + o0;
  out[n * D_F + c + 1] = h[n * D_F + c + 1] + o1;
}

__global__ void egcl_zero_kernel(float* __restrict__ p, int n) {
  int i = blockIdx.x * 256 + threadIdx.x;
  if (i < n) p[i] = 0.f;
}

extern "C" void kernel_launch(void* const* d_in, const int* in_sizes, int n_in,
                              void* d_out, int out_size, void* d_ws, size_t ws_size,
                              hipStream_t stream) {
  (void)in_sizes; (void)n_in; (void)out_size; (void)ws_size;
  const float* h         = (const float*)d_in[0];
  const float* coord     = (const float*)d_in[1];
  const float* edge_mask = (const float*)d_in[2];
  const float* We1       = (const float*)d_in[3];
  const float* be1       = (const float*)d_in[4];
  const float* We2       = (const float*)d_in[5];
  const float* be2       = (const float*)d_in[6];
  const float* Wn1       = (const float*)d_in[7];
  const float* bn1       = (const float*)d_in[8];
  const float* Wn2       = (const float*)d_in[9];
  const float* bn2       = (const float*)d_in[10];
  const int*   ei        = (const int*)d_in[11];
  float* out = (float*)d_out;
  float* agg = (float*)d_ws;  // N*D floats = 5.12 MB

  hipFuncSetAttribute((const void*)egcl_edge_kernel,
                      hipFuncAttributeMaxDynamicSharedMemorySize, (int)EDGE_LDS);

  egcl_zero_kernel<<<(N_NODES * D_F + 255) / 256, 256, 0, stream>>>(agg, N_NODES * D_F);
  egcl_edge_kernel<<<EDGE_BLOCKS, EDGE_THREADS, EDGE_LDS, stream>>>(
      h, coord, edge_mask, We1, be1, We2, be2, ei, agg);
  egcl_node_kernel<<<N_NODES / 4, 256, 0, stream>>>(h, agg, Wn1, bn1, Wn2, bn2, out);
}

// Round 3
// 181.232 us; speedup vs baseline: 1.5782x; 1.5782x over previous
//
#include <hip/hip_runtime.h>

#define D_F 128
#define N_NODES 10000
#define N_EDGES 320000
#define TE 64
#define EDGE_BLOCKS 768

typedef short s16x8 __attribute__((ext_vector_type(8)));
typedef float f32x4 __attribute__((ext_vector_type(4)));

union FragU { s16x8 v; unsigned u[4]; };

__device__ __forceinline__ unsigned cvt_pk_bf16(float lo, float hi) {
  unsigned r;
  asm("v_cvt_pk_bf16_f32 %0, %1, %2" : "=v"(r) : "v"(lo), "v"(hi));
  return r;
}
__device__ __forceinline__ float silu_f(float x) {
  float t = __builtin_amdgcn_exp2f(x * -1.44269504089f);
  return x * __builtin_amdgcn_rcpf(1.0f + t);
}
__device__ __forceinline__ void bar_lds() {
  asm volatile("s_waitcnt lgkmcnt(0)" ::: "memory");
  __builtin_amdgcn_sched_barrier(0);
  __builtin_amdgcn_s_barrier();
  __builtin_amdgcn_sched_barrier(0);
}

// ---- edge kernel LDS map (bytes) ----
// A  : [64 e][256 k] bf16, row 512B, 16B-granule swizzle: byte ^= ((e&7)<<4)
// M1 : [64 e][128 k] bf16, row 256B, same swizzle
#define OFF_A    0u
#define OFF_M1   32768u
#define OFF_META 49152u
#define EDGE_LDS (49152u + 1024u)

__global__ __launch_bounds__(256)
void egcl_edge_kernel(const float* __restrict__ h, const float* __restrict__ coord,
                      const float* __restrict__ edge_mask,
                      const float* __restrict__ We1, const float* __restrict__ be1,
                      const float* __restrict__ We2, const float* __restrict__ be2,
                      const int* __restrict__ ei, float* __restrict__ agg) {
  extern __shared__ __attribute__((aligned(16))) char smem[];
  const int tid  = threadIdx.x;
  const int lane = tid & 63;
  const int wv   = tid >> 6;          // 0..3  (col group)
  const int l15  = lane & 15;
  const int lg   = lane >> 4;         // 0..3
  const int c0   = wv * 32;
  const int col0 = c0 + l15;

  int*   rows = (int*)(smem + OFF_META);
  float* rads = (float*)(smem + OFF_META + 256);
  float* msks = (float*)(smem + OFF_META + 512);

  // ---- per-wave weight fragments in registers (bf16) ----
  FragU bw1[8][2];   // [ktile of 32][nt]
  FragU bw2[4][2];
#pragma unroll
  for (int kt = 0; kt < 8; ++kt)
#pragma unroll
    for (int nt = 0; nt < 2; ++nt) {
      const int col = col0 + nt * 16;
      const int kb = kt * 32 + lg * 8;
#pragma unroll
      for (int j = 0; j < 4; ++j)
        bw1[kt][nt].u[j] = cvt_pk_bf16(We1[(kb + 2 * j) * D_F + col],
                                       We1[(kb + 2 * j + 1) * D_F + col]);
    }
#pragma unroll
  for (int kt = 0; kt < 4; ++kt)
#pragma unroll
    for (int nt = 0; nt < 2; ++nt) {
      const int col = col0 + nt * 16;
      const int kb = kt * 32 + lg * 8;
#pragma unroll
      for (int j = 0; j < 4; ++j)
        bw2[kt][nt].u[j] = cvt_pk_bf16(We2[(kb + 2 * j) * D_F + col],
                                       We2[(kb + 2 * j + 1) * D_F + col]);
    }
  const float bv1[2] = {be1[col0], be1[col0 + 16]};
  const float wlv[2] = {We1[256 * D_F + col0], We1[256 * D_F + col0 + 16]};
  const float bv2[2] = {be2[col0], be2[col0 + 16]};

  const int se = tid >> 2;   // staging edge 0..63
  const int sq = tid & 3;    // staging k-quarter
  const unsigned sswz = (unsigned)((se & 7) << 4);
  const unsigned rswz = (unsigned)((l15 & 7) << 4);

  const int ntiles = N_EDGES / TE;
  for (int tile = (int)blockIdx.x; tile < ntiles; tile += (int)gridDim.x) {
    const int ebase = tile * TE;

    // ---- stage meta + A tile ----
    const int n0 = ei[ebase + se];
    const int n1 = ei[N_EDGES + ebase + se];
    if (sq == 0) {
      float dx = coord[n0 * 3 + 0] - coord[n1 * 3 + 0];
      float dy = coord[n0 * 3 + 1] - coord[n1 * 3 + 1];
      float dz = coord[n0 * 3 + 2] - coord[n1 * 3 + 2];
      rows[se] = n0;
      rads[se] = dx * dx + dy * dy + dz * dz;
      msks[se] = edge_mask[ebase + se];
    }
#pragma unroll
    for (int p = 0; p < 2; ++p) {
      const f32x4* src = (const f32x4*)(h + (p ? n1 : n0) * D_F + sq * 32);
#pragma unroll
      for (int j = 0; j < 4; ++j) {
        f32x4 x0 = src[2 * j], x1 = src[2 * j + 1];
        FragU w;
        w.u[0] = cvt_pk_bf16(x0[0], x0[1]);
        w.u[1] = cvt_pk_bf16(x0[2], x0[3]);
        w.u[2] = cvt_pk_bf16(x1[0], x1[1]);
        w.u[3] = cvt_pk_bf16(x1[2], x1[3]);
        // byte offset within the 512B row: p-half=256B, sq-quarter=64B, j=16B
        unsigned kb = (unsigned)(p * 256 + sq * 64 + j * 16);
        *(s16x8*)(smem + OFF_A + (unsigned)(se * 512) + (kb ^ sswz)) = w.v;
      }
    }
    bar_lds();

    // ---- GEMM1: [64x256] @ We1 -> m1 ----
    f32x4 acc[4][2];
#pragma unroll
    for (int mt = 0; mt < 4; ++mt)
#pragma unroll
      for (int nt = 0; nt < 2; ++nt) acc[mt][nt] = (f32x4){0.f, 0.f, 0.f, 0.f};
#pragma unroll
    for (int ks = 0; ks < 8; ++ks) {
      s16x8 a[4];
      unsigned kb = ((unsigned)((ks * 32 + lg * 8) * 2)) ^ rswz;
#pragma unroll
      for (int mt = 0; mt < 4; ++mt)
        a[mt] = *(const s16x8*)(smem + OFF_A + (unsigned)((mt * 16 + l15) * 512) + kb);
#pragma unroll
      for (int mt = 0; mt < 4; ++mt)
#pragma unroll
        for (int nt = 0; nt < 2; ++nt)
          acc[mt][nt] = __builtin_amdgcn_mfma_f32_16x16x32_bf16(a[mt], bw1[ks][nt].v,
                                                                acc[mt][nt], 0, 0, 0);
    }
    // epilogue 1: + be1 + radial*w_last, silu -> m1 (bf16)
#pragma unroll
    for (int mt = 0; mt < 4; ++mt)
#pragma unroll
      for (int nt = 0; nt < 2; ++nt)
#pragma unroll
        for (int q = 0; q < 4; ++q) {
          int e = mt * 16 + lg * 4 + q;
          float v = acc[mt][nt][q] + bv1[nt] + rads[e] * wlv[nt];
          v = silu_f(v);
          unsigned pw = cvt_pk_bf16(v, v);
          *(unsigned short*)(smem + OFF_M1 + (unsigned)(e * 256) +
                             ((unsigned)((c0 + nt * 16 + l15) * 2) ^
                              ((unsigned)((e & 7) << 4)))) = (unsigned short)pw;
        }
    bar_lds();

    // ---- GEMM2: m1 @ We2 -> silu -> *mask -> atomicAdd ----
#pragma unroll
    for (int mt = 0; mt < 4; ++mt)
#pragma unroll
      for (int nt = 0; nt < 2; ++nt) acc[mt][nt] = (f32x4){0.f, 0.f, 0.f, 0.f};
#pragma unroll
    for (int ks = 0; ks < 4; ++ks) {
      s16x8 a[4];
      unsigned kb = ((unsigned)((ks * 32 + lg * 8) * 2)) ^ rswz;
#pragma unroll
      for (int mt = 0; mt < 4; ++mt)
        a[mt] = *(const s16x8*)(smem + OFF_M1 + (unsigned)((mt * 16 + l15) * 256) + kb);
#pragma unroll
      for (int mt = 0; mt < 4; ++mt)
#pragma unroll
        for (int nt = 0; nt < 2; ++nt)
          acc[mt][nt] = __builtin_amdgcn_mfma_f32_16x16x32_bf16(a[mt], bw2[ks][nt].v,
                                                                acc[mt][nt], 0, 0, 0);
    }
#pragma unroll
    for (int mt = 0; mt < 4; ++mt)
#pragma unroll
      for (int q = 0; q < 4; ++q) {
        int e = mt * 16 + lg * 4 + q;
        int r = rows[e];
        float mk = msks[e];
#pragma unroll
        for (int nt = 0; nt < 2; ++nt) {
          float v = silu_f(acc[mt][nt][q] + bv2[nt]) * mk;
          atomicAdd(agg + (size_t)r * D_F + c0 + nt * 16 + l15, v);
        }
      }
    bar_lds();
  }
}

// ---- node kernel: same MFMA structure, K1=256 (h||agg), K2=128, residual ----
#define NODE_LDS 49152u

__global__ __launch_bounds__(256)
void egcl_node_kernel(const float* __restrict__ h, const float* __restrict__ agg,
                      const float* __restrict__ Wn1, const float* __restrict__ bn1,
                      const float* __restrict__ Wn2, const float* __restrict__ bn2,
                      float* __restrict__ out) {
  extern __shared__ __attribute__((aligned(16))) char smem[];
  const int tid  = threadIdx.x;
  const int lane = tid & 63;
  const int wv   = tid >> 6;
  const int l15  = lane & 15;
  const int lg   = lane >> 4;
  const int c0   = wv * 32;
  const int col0 = c0 + l15;
  const int base = blockIdx.x * 64;

  FragU bw1[8][2];
  FragU bw2[4][2];
#pragma unroll
  for (int kt = 0; kt < 8; ++kt)
#pragma unroll
    for (int nt = 0; nt < 2; ++nt) {
      const int col = col0 + nt * 16;
      const int kb = kt * 32 + lg * 8;
#pragma unroll
      for (int j = 0; j < 4; ++j)
        bw1[kt][nt].u[j] = cvt_pk_bf16(Wn1[(kb + 2 * j) * D_F + col],
                                       Wn1[(kb + 2 * j + 1) * D_F + col]);
    }
#pragma unroll
  for (int kt = 0; kt < 4; ++kt)
#pragma unroll
    for (int nt = 0; nt < 2; ++nt) {
      const int col = col0 + nt * 16;
      const int kb = kt * 32 + lg * 8;
#pragma unroll
      for (int j = 0; j < 4; ++j)
        bw2[kt][nt].u[j] = cvt_pk_bf16(Wn2[(kb + 2 * j) * D_F + col],
                                       Wn2[(kb + 2 * j + 1) * D_F + col]);
    }
  const float bv1[2] = {bn1[col0], bn1[col0 + 16]};
  const float bv2[2] = {bn2[col0], bn2[col0 + 16]};

  const int se = tid >> 2;
  const int sq = tid & 3;
  const unsigned sswz = (unsigned)((se & 7) << 4);
  const unsigned rswz = (unsigned)((l15 & 7) << 4);
  const int node = base + se;

  // stage A = [h || agg] bf16
#pragma unroll
  for (int p = 0; p < 2; ++p) {
    FragU w;
    if (node < N_NODES) {
      const f32x4* src = (const f32x4*)((p ? agg : h) + node * D_F + sq * 32);
#pragma unroll
      for (int j = 0; j < 4; ++j) {
        f32x4 x0 = src[2 * j], x1 = src[2 * j + 1];
        w.u[0] = cvt_pk_bf16(x0[0], x0[1]);
        w.u[1] = cvt_pk_bf16(x0[2], x0[3]);
        w.u[2] = cvt_pk_bf16(x1[0], x1[1]);
        w.u[3] = cvt_pk_bf16(x1[2], x1[3]);
        unsigned kb = (unsigned)(p * 256 + sq * 64 + j * 16);
        *(s16x8*)(smem + OFF_A + (unsigned)(se * 512) + (kb ^ sswz)) = w.v;
      }
    } else {
      w.u[0] = w.u[1] = w.u[2] = w.u[3] = 0u;
#pragma unroll
      for (int j = 0; j < 4; ++j) {
        unsigned kb = (unsigned)(p * 256 + sq * 64 + j * 16);
        *(s16x8*)(smem + OFF_A + (unsigned)(se * 512) + (kb ^ sswz)) = w.v;
      }
    }
  }
  bar_lds();

  f32x4 acc[4][2];
#pragma unroll
  for (int mt = 0; mt < 4; ++mt)
#pragma unroll
    for (int nt = 0; nt < 2; ++nt) acc[mt][nt] = (f32x4){0.f, 0.f, 0.f, 0.f};
#pragma unroll
  for (int ks = 0; ks < 8; ++ks) {
    s16x8 a[4];
    unsigned kb = ((unsigned)((ks * 32 + lg * 8) * 2)) ^ rswz;
#pragma unroll
    for (int mt = 0; mt < 4; ++mt)
      a[mt] = *(const s16x8*)(smem + OFF_A + (unsigned)((mt * 16 + l15) * 512) + kb);
#pragma unroll
    for (int mt = 0; mt < 4; ++mt)
#pragma unroll
      for (int nt = 0; nt < 2; ++nt)
        acc[mt][nt] = __builtin_amdgcn_mfma_f32_16x16x32_bf16(a[mt], bw1[ks][nt].v,
                                                              acc[mt][nt], 0, 0, 0);
  }
#pragma unroll
  for (int mt = 0; mt < 4; ++mt)
#pragma unroll
    for (int nt = 0; nt < 2; ++nt)
#pragma unroll
      for (int q = 0; q < 4; ++q) {
        int e = mt * 16 + lg * 4 + q;
        float v = silu_f(acc[mt][nt][q] + bv1[nt]);
        unsigned pw = cvt_pk_bf16(v, v);
        *(unsigned short*)(smem + OFF_M1 + (unsigned)(e * 256) +
                           ((unsigned)((c0 + nt * 16 + l15) * 2) ^
                            ((unsigned)((e & 7) << 4)))) = (unsigned short)pw;
      }
  bar_lds();

#pragma unroll
  for (int mt = 0; mt < 4; ++mt)
#pragma unroll
    for (int nt = 0; nt < 2; ++nt) acc[mt][nt] = (f32x4){0.f, 0.f, 0.f, 0.f};
#pragma unroll
  for (int ks = 0; ks < 4; ++ks) {
    s16x8 a[4];
    unsigned kb = ((unsigned)((ks * 32 + lg * 8) * 2)) ^ rswz;
#pragma unroll
    for (int mt = 0; mt < 4; ++mt)
      a[mt] = *(const s16x8*)(smem + OFF_M1 + (unsigned)((mt * 16 + l15) * 256) + kb);
#pragma unroll
    for (int mt = 0; mt < 4; ++mt)
#pragma unroll
      for (int nt = 0; nt < 2; ++nt)
        acc[mt][nt] = __builtin_amdgcn_mfma_f32_16x16x32_bf16(a[mt], bw2[ks][nt].v,
                                                              acc[mt][nt], 0, 0, 0);
  }
#pragma unroll
  for (int mt = 0; mt < 4; ++mt)
#pragma unroll
    for (int q = 0; q < 4; ++q) {
      int nd = base + mt * 16 + lg * 4 + q;
      if (nd < N_NODES) {
#pragma unroll
        for (int nt = 0; nt < 2; ++nt) {
          int col = c0 + nt * 16 + l15;
          out[nd * D_F + col] = h[nd * D_F + col] + acc[mt][nt][q] + bv2[nt];
        }
      }
    }
}

extern "C" void kernel_launch(void* const* d_in, const int* in_sizes, int n_in,
                              void* d_out, int out_size, void* d_ws, size_t ws_size,
                              hipStream_t stream) {
  (void)in_sizes; (void)n_in; (void)out_size; (void)ws_size;
  const float* h         = (const float*)d_in[0];
  const float* coord     = (const float*)d_in[1];
  const float* edge_mask = (const float*)d_in[2];
  const float* We1       = (const float*)d_in[3];
  const float* be1       = (const float*)d_in[4];
  const float* We2       = (const float*)d_in[5];
  const float* be2       = (const float*)d_in[6];
  const float* Wn1       = (const float*)d_in[7];
  const float* bn1       = (const float*)d_in[8];
  const float* Wn2       = (const float*)d_in[9];
  const float* bn2       = (const float*)d_in[10];
  const int*   ei        = (const int*)d_in[11];
  float* out = (float*)d_out;
  float* agg = (float*)d_ws;  // N*D floats = 5.12 MB

  hipFuncSetAttribute((const void*)egcl_edge_kernel,
                      hipFuncAttributeMaxDynamicSharedMemorySize, (int)EDGE_LDS);
  hipFuncSetAttribute((const void*)egcl_node_kernel,
                      hipFuncAttributeMaxDynamicSharedMemorySize, (int)NODE_LDS);

  hipMemsetAsync(agg, 0, (size_t)N_NODES * D_F * sizeof(float), stream);
  egcl_edge_kernel<<<EDGE_BLOCKS, 256, EDGE_LDS, stream>>>(
      h, coord, edge_mask, We1, be1, We2, be2, ei, agg);
  egcl_node_kernel<<<(N_NODES + 63) / 64, 256, NODE_LDS, stream>>>(
      h, agg, Wn1, bn1, Wn2, bn2, out);
}